// Round 11
// baseline (2693.683 us; speedup 1.0000x reference)
//
#include <hip/hip_runtime.h>
#include <stdint.h>

// SEQ=256, B=64, DIM=1024, UNITS=1024, 4U=4096
typedef unsigned short ushort_t;
typedef __attribute__((ext_vector_type(8))) short s16x8;
typedef __attribute__((ext_vector_type(4))) float f32x4;
typedef __attribute__((ext_vector_type(4))) unsigned short u16x4;

#define TO_GLB(p) ((const __attribute__((address_space(1))) void*)(p))
#define TO_LDS(p) ((__attribute__((address_space(3))) void*)(p))

__device__ __forceinline__ ushort_t f2bf(float f) {
  union { float f; uint32_t u; } v; v.f = f;
  uint32_t u = v.u;
  uint32_t r = (u + 0x7FFFu + ((u >> 16) & 1u)) >> 16;
  return (ushort_t)r;
}
__device__ __forceinline__ float bf2f(ushort_t b) {
  union { uint32_t u; float f; } v; v.u = ((uint32_t)b) << 16;
  return v.f;
}
__device__ __forceinline__ float sigm(float x) {
  x = fminf(fmaxf(x, -30.f), 30.f);
  return 1.0f / (1.0f + __expf(-x));
}
__device__ __forceinline__ float tanh_f(float x) {
  x = fminf(fmaxf(x, -15.f), 15.f);
  float t = __expf(2.0f * x);
  return (t - 1.0f) / (t + 1.0f);
}

// ---------------- convert f32 -> bf16, 4 elems/thread ----------------
__global__ void conv_f32_to_bf16(const float* __restrict__ src,
                                 ushort_t* __restrict__ dst, int n4) {
  int i = blockIdx.x * blockDim.x + threadIdx.x;
  if (i < n4) {
    float4 v = ((const float4*)src)[i];
    u16x4 o;
    o[0] = f2bf(v.x); o[1] = f2bf(v.y); o[2] = f2bf(v.z); o[3] = f2bf(v.w);
    *(u16x4*)(dst + 4 * (size_t)i) = o;
  }
}

// ---------------- init h0 (bf16) from hx ----------------
__global__ void init_h(const float* __restrict__ hx, ushort_t* __restrict__ h0, int n) {
  int i = blockIdx.x * blockDim.x + threadIdx.x;
  if (i < n) h0[i] = f2bf(hx[i]);
}

// ---------------- persistent LSTM scan with FUSED x-projection ----------
// 256 blocks = 4 batch-groups x 64 unit-groups; 512 thr, 8 waves (r6 base,
// the 1290us relay). NEW: no separate xproj GEMM. Waves 4-7 compute the
// block's xproj slice [16b x 64 gate-rows] for timestep s+3 (128 MFMAs +
// L2-resident W_ih/x streaming) into a 4-slot LDS ring DURING the ~4us
// relay-wait window after the flag release. Critical path = r6 unchanged.
__global__ __launch_bounds__(512, 2) void lstm_scan(
    const ushort_t* __restrict__ whhb,   // W_hh bf16 [4096][1024]
    const ushort_t* __restrict__ xbf,    // x bf16 [256][64][1024]
    const ushort_t* __restrict__ wihb,   // W_ih bf16 [4096][1024]
    const float* __restrict__ b_ih, const float* __restrict__ b_hh,
    const float* __restrict__ reset,     // f32 [256*64]
    const float* __restrict__ cxp,       // f32 [64*1024]
    ushort_t* __restrict__ h0buf, ushort_t* __restrict__ h1buf,
    unsigned int* __restrict__ flags,    // [256], zeroed before launch
    float* __restrict__ out_h0, float* __restrict__ out_h1,
    float* __restrict__ out_cs)
{
  __shared__ char smem[59904];
  char* hs = smem;                        // h tile [16][2048B], XOR-swizzled
  float* gsh = (float*)(smem + 32768);    // [2 kh][16 batch][84] gate partials
  float* ring = (float*)(smem + 43520);   // xproj ring [4 slot][16 b][64 c] f32

  const int t = threadIdx.x;
  const int lane = t & 63;
  const int w = t >> 6;
  const int ns = w & 3;          // gate section
  const int kh = w >> 2;         // K half
  const int j16 = lane & 15;
  const int q = lane >> 4;
  const int blk = blockIdx.x;
  const int bg = blk >> 6;       // batch group 0..3
  const int ug = blk & 63;       // unit group 0..63
  const int b0 = bg * 16;
  const int u0 = ug * 16;

  // ---- permanent weight fragments: 16 x s16x8 = 64 VGPR ----
  s16x8 bfrag[16];
  {
    const ushort_t* wrow = whhb + ((size_t)(ns * 1024 + u0 + j16)) * 1024 + kh * 512 + q * 8;
#pragma unroll
    for (int kk = 0; kk < 16; kk++)
      bfrag[kk] = *(const s16x8*)(wrow + kk * 32);
  }
#pragma unroll
  for (int kk = 0; kk < 16; kk++)
    asm volatile("" : "+v"(bfrag[kk]));

  // ---- persistent cell state: threads 0..255 own one (b_local, lu) cell ----
  const int b_local = t >> 4;    // valid for t<256: 0..15
  const int lu = t & 15;
  const bool upd = (t < 256);
  float c_reg = 0.0f;
  if (upd) c_reg = cxp[(size_t)(b0 + b_local) * 1024 + u0 + lu];

  // ---- xproj duty (waves 4..7): column c = gate-col of this block's slice ----
  const bool xw = (w >= 4);
  const int xc_col = (w - 4) * 16 + j16;                       // 0..63
  const int wrow_i = ((xc_col & 3) << 10) + u0 + (xc_col >> 2); // W_ih row
  const ushort_t* wih_p = wihb + (size_t)wrow_i * 1024 + q * 8;
  float biasv = 0.0f;
  if (xw) biasv = b_ih[wrow_i] + b_hh[wrow_i];

  const f32x4 fzero = {0.f, 0.f, 0.f, 0.f};
  auto do_xproj = [&](int T) {
    f32x4 ax = fzero;
    const ushort_t* xrow = xbf + ((size_t)T * 64 + b0 + j16) * 1024 + q * 8;
#pragma unroll 8
    for (int kk = 0; kk < 32; kk++) {
      s16x8 a = *(const s16x8*)(xrow + kk * 32);
      s16x8 bw = *(const s16x8*)(wih_p + kk * 32);
      ax = __builtin_amdgcn_mfma_f32_16x16x32_bf16(a, bw, ax, 0, 0, 0);
    }
    float* rp = ring + (size_t)((T & 3) * 16) * 64 + xc_col;
#pragma unroll
    for (int r = 0; r < 4; r++)
      rp[(q * 4 + r) * 64] = ax[r] + biasv;
  };

  // prologue: fill ring for timesteps 0,1,2
  if (xw) { do_xproj(0); do_xproj(1); do_xproj(2); }

  // staging coords: thread owns row sr, 64B chunk sc
  const int sr = t & 15;
  const int sc = t >> 4;         // 0..31
  const int swz = (sr & 7) << 4;
  const s16x8 zv = {0, 0, 0, 0, 0, 0, 0, 0};

  for (int s = 0; s < 256; s++) {
    const ushort_t* hc = (s & 1) ? h1buf : h0buf;
    ushort_t* hn = (s & 1) ? h0buf : h1buf;

    float m2 = 0.0f;
    if (upd) m2 = 1.0f - reset[s * 64 + b0 + b_local];
    float mrow = reset[s * 64 + b0 + sr];

    // ---- per-wave poll of the 64 producers of our batch-group ----
    if (s > 0) {
      const unsigned int* fp = flags + bg * 64 + lane;
      while (__hip_atomic_load(fp, __ATOMIC_RELAXED, __HIP_MEMORY_SCOPE_AGENT)
             < (unsigned int)s) {}
      asm volatile("" ::: "memory");   // keep staging loads below the poll
    }

    // ---- stage h[16][1024] -> LDS: 4 x b128 sc0/sc1 loads (LLC-coherent) ----
    {
      const char* srcp = (const char*)(hc + (size_t)(b0 + sr) * 1024 + sc * 32);
      s16x8 v0, v1, v2, v3;
      asm volatile("global_load_dwordx4 %0, %1, off sc0 sc1" : "=v"(v0) : "v"(srcp));
      asm volatile("global_load_dwordx4 %0, %1, off offset:16 sc0 sc1" : "=v"(v1) : "v"(srcp));
      asm volatile("global_load_dwordx4 %0, %1, off offset:32 sc0 sc1" : "=v"(v2) : "v"(srcp));
      asm volatile("global_load_dwordx4 %0, %1, off offset:48 sc0 sc1" : "=v"(v3) : "v"(srcp));
      asm volatile("s_waitcnt vmcnt(0)" ::: "memory");
      __builtin_amdgcn_sched_barrier(0);
      if (mrow != 0.0f) { v0 = zv; v1 = zv; v2 = zv; v3 = zv; }  // episode reset
      const int base = sr * 2048 + sc * 64;
      *(s16x8*)(hs + ((base + 0)  ^ swz)) = v0;
      *(s16x8*)(hs + ((base + 16) ^ swz)) = v1;
      *(s16x8*)(hs + ((base + 32) ^ swz)) = v2;
      *(s16x8*)(hs + ((base + 48) ^ swz)) = v3;
    }
    __syncthreads();

    // ---- MFMA: wave computes gates[16 batch][16 units of gate ns], K=512 ----
    f32x4 acc = fzero;
#pragma unroll
    for (int kk = 0; kk < 16; kk++) {
      int off = (j16 * 2048 + kh * 1024 + kk * 64 + q * 16) ^ ((j16 & 7) << 4);
      s16x8 a = *(const s16x8*)(hs + off);
      acc = __builtin_amdgcn_mfma_f32_16x16x32_bf16(a, bfrag[kk], acc, 0, 0, 0);
    }
#pragma unroll
    for (int kk = 0; kk < 16; kk++)
      asm volatile("" : "+v"(bfrag[kk]));

    // ---- stash partial gates: gsh[kh][batch=q*4+jj][ns*16+j16] ----
#pragma unroll
    for (int jj = 0; jj < 4; jj++)
      gsh[kh * 1344 + (q * 4 + jj) * 84 + ns * 16 + j16] = acc[jj];
    __syncthreads();

    // ---- cell update (threads 0..255, 1 cell each) ----
    float hv = 0.0f, cn = 0.0f;
    if (upd) {
      const float* g0p = gsh + b_local * 84;
      const float* g1p = gsh + 1344 + b_local * 84;
      // xproj from the LDS ring: c = lu*4 + gate -> one contiguous f32x4
      f32x4 rv = *(const f32x4*)(ring + (size_t)((s & 3) * 16 + b_local) * 64 + lu * 4);
      float gv0 = g0p[lu]      + g1p[lu]      + rv[0];
      float gv1 = g0p[16 + lu] + g1p[16 + lu] + rv[1];
      float gv2 = g0p[32 + lu] + g1p[32 + lu] + rv[2];
      float gv3 = g0p[48 + lu] + g1p[48 + lu] + rv[3];
      float ii = sigm(gv0), ff = sigm(gv1), G = tanh_f(gv2), oo = sigm(gv3);
      cn = ff * (c_reg * m2) + ii * G;
      hv = oo * tanh_f(cn);
      c_reg = cn;

      // h store: pack lane pairs -> one 4B agent-scope (sc1) store
      unsigned int mybits = (unsigned int)f2bf(hv);
      unsigned int pb = (unsigned int)__shfl_xor((int)mybits, 1, 64);
      if ((t & 1) == 0) {
        unsigned int pack = mybits | (pb << 16);
        __hip_atomic_store(
            (unsigned int*)(hn + (size_t)(b_local + b0) * 1024 + u0 + lu),
            pack, __ATOMIC_RELAXED, __HIP_MEMORY_SCOPE_AGENT);
      }
    }

    // drain h stores, join all waves, release flag
    asm volatile("s_waitcnt vmcnt(0)" ::: "memory");
    __syncthreads();
    if (t == 0)
      __hip_atomic_store(&flags[blk], (unsigned int)(s + 1),
                         __ATOMIC_RELAXED, __HIP_MEMORY_SCOPE_AGENT);

    // ---- off-critical-path work, hidden under next relay wait ----
    if (upd) {
      size_t ob = ((size_t)s * 64 + b0 + b_local) * 1024 + u0 + lu;
      out_cs[ob] = cn;
      out_h0[ob] = hv;
      out_h1[ob] = hv;
    }
    if (xw && (s + 3 < 256)) do_xproj(s + 3);   // waves 4-7: next xproj slice
  }
}

extern "C" void kernel_launch(void* const* d_in, const int* in_sizes, int n_in,
                              void* d_out, int out_size, void* d_ws, size_t ws_size,
                              hipStream_t stream) {
  const float* x     = (const float*)d_in[0];
  const float* hx    = (const float*)d_in[1];
  const float* cx    = (const float*)d_in[2];
  const float* reset = (const float*)d_in[3];
  const float* W_ih  = (const float*)d_in[4];
  const float* W_hh  = (const float*)d_in[5];
  const float* b_ih  = (const float*)d_in[6];
  const float* b_hh  = (const float*)d_in[7];
  float* out = (float*)d_out;

  char* ws = (char*)d_ws;
  ushort_t* xbf   = (ushort_t*)(ws);                  // 33,554,432 B
  ushort_t* wihb  = (ushort_t*)(ws + 33554432);       //  8,388,608 B
  ushort_t* whhb  = (ushort_t*)(ws + 41943040);       //  8,388,608 B
  ushort_t* h0    = (ushort_t*)(ws + 50331648);       // 131,072 B
  ushort_t* h1    = (ushort_t*)(ws + 50462720);       // 131,072 B
  unsigned int* flags = (unsigned int*)(ws + 50593792);  // 1,024 B

  hipMemsetAsync(flags, 0, 1024, stream);
  hipLaunchKernelGGL(conv_f32_to_bf16, dim3(16384), dim3(256), 0, stream, x, xbf, 4194304);
  hipLaunchKernelGGL(conv_f32_to_bf16, dim3(4096), dim3(256), 0, stream, W_ih, wihb, 1048576);
  hipLaunchKernelGGL(conv_f32_to_bf16, dim3(4096), dim3(256), 0, stream, W_hh, whhb, 1048576);
  hipLaunchKernelGGL(init_h, dim3(256), dim3(256), 0, stream, hx, h0, 65536);

  float* oh0 = out;
  float* oh1 = out + 16777216;
  float* ocs = out + 33554432;

  const ushort_t* whhb_c = whhb;
  const ushort_t* xbf_c = xbf;
  const ushort_t* wihb_c = wihb;
  void* args[] = {(void*)&whhb_c, (void*)&xbf_c, (void*)&wihb_c,
                  (void*)&b_ih, (void*)&b_hh, (void*)&reset, (void*)&cx,
                  (void*)&h0, (void*)&h1, (void*)&flags,
                  (void*)&oh0, (void*)&oh1, (void*)&ocs};
  hipLaunchCooperativeKernel((void*)lstm_scan, dim3(256), dim3(512), args, 0, stream);
}

// Round 13
// 1516.763 us; speedup vs baseline: 1.7759x; 1.7759x over previous
//
#include <hip/hip_runtime.h>
#include <stdint.h>

// SEQ=256, B=64, DIM=1024, UNITS=1024, 4U=4096
typedef unsigned short ushort_t;
typedef __attribute__((ext_vector_type(8))) short s16x8;
typedef __attribute__((ext_vector_type(4))) float f32x4;
typedef __attribute__((ext_vector_type(4))) unsigned short u16x4;

#define TO_GLB(p) ((const __attribute__((address_space(1))) void*)(p))
#define TO_LDS(p) ((__attribute__((address_space(3))) void*)(p))

__device__ __forceinline__ ushort_t f2bf(float f) {
  union { float f; uint32_t u; } v; v.f = f;
  uint32_t u = v.u;
  uint32_t r = (u + 0x7FFFu + ((u >> 16) & 1u)) >> 16;
  return (ushort_t)r;
}
__device__ __forceinline__ float bf2f(ushort_t b) {
  union { uint32_t u; float f; } v; v.u = ((uint32_t)b) << 16;
  return v.f;
}
__device__ __forceinline__ float sigm(float x) {
  x = fminf(fmaxf(x, -30.f), 30.f);
  return 1.0f / (1.0f + __expf(-x));
}
__device__ __forceinline__ float tanh_f(float x) {
  x = fminf(fmaxf(x, -15.f), 15.f);
  float t = __expf(2.0f * x);
  return (t - 1.0f) / (t + 1.0f);
}

// ---------------- fused prep: convert x/W_ih/W_hh to bf16 + init h0 -------
// one grid-strided kernel replaces 4 small launches.
// region sizes in float4 units (r12 bug: these were 4x too small for x/W):
//   x:    256*64*1024 fl = 4,194,304 f4
//   W_ih: 4096*1024   fl = 1,048,576 f4   (W_hh same)
//   hx:   64*1024     fl =    16,384 f4
#define PREP_NX 4194304
#define PREP_NW 1048576
#define PREP_NH 16384
__global__ void prep_all(const float* __restrict__ x,
                         const float* __restrict__ W_ih,
                         const float* __restrict__ W_hh,
                         const float* __restrict__ hx,
                         ushort_t* __restrict__ xbf,
                         ushort_t* __restrict__ wihb,
                         ushort_t* __restrict__ whhb,
                         ushort_t* __restrict__ h0) {
  const int total = PREP_NX + 2 * PREP_NW + PREP_NH;
  for (int i = blockIdx.x * blockDim.x + threadIdx.x; i < total;
       i += gridDim.x * blockDim.x) {
    const float* src; ushort_t* dst; int j;
    if (i < PREP_NX)                     { src = x;    dst = xbf;  j = i; }
    else if (i < PREP_NX + PREP_NW)      { src = W_ih; dst = wihb; j = i - PREP_NX; }
    else if (i < PREP_NX + 2 * PREP_NW)  { src = W_hh; dst = whhb; j = i - PREP_NX - PREP_NW; }
    else                                 { src = hx;   dst = h0;   j = i - PREP_NX - 2 * PREP_NW; }
    float4 v = ((const float4*)src)[j];
    u16x4 o;
    o[0] = f2bf(v.x); o[1] = f2bf(v.y); o[2] = f2bf(v.z); o[3] = f2bf(v.w);
    *(u16x4*)(dst + 4 * (size_t)j) = o;
  }
}

// ---------------- x_proj GEMM: C[16384][4096] = A @ W_ih^T + b_ih + b_hh ----
__global__ __launch_bounds__(256) void gemm_xproj(
    const ushort_t* __restrict__ A,   // x bf16 [16384][1024]
    const ushort_t* __restrict__ Bw,  // W_ih bf16 [4096][1024]
    const float* __restrict__ b_ih, const float* __restrict__ b_hh,
    ushort_t* __restrict__ C)         // x_proj bf16 [16384][4096]
{
  __shared__ ushort_t As[128 * 32];
  __shared__ ushort_t Bs[128 * 32];
  const int t = threadIdx.x;
  const int lane = t & 63;
  const int wid = t >> 6;
  const int wr = wid >> 1, wc = wid & 1;
  const size_t tm = (size_t)blockIdx.x * 128;
  const size_t tn = (size_t)blockIdx.y * 128;

  f32x4 acc[4][4];
  const f32x4 zero = {0.f, 0.f, 0.f, 0.f};
#pragma unroll
  for (int m = 0; m < 4; m++)
#pragma unroll
    for (int n = 0; n < 4; n++) acc[m][n] = zero;

  for (int k0 = 0; k0 < 1024; k0 += 32) {
    __syncthreads();
#pragma unroll
    for (int i = 0; i < 2; i++) {
      int row = i * 64 + (t >> 2);
      int kc = (t & 3) * 8;
      const ushort_t* ga = A + (tm + row) * 1024 + k0 + kc;
      __builtin_amdgcn_global_load_lds(TO_GLB(ga),
          TO_LDS((char*)As + (i * 256 + wid * 64) * 16), 16, 0, 0);
      const ushort_t* gb = Bw + (tn + row) * 1024 + k0 + kc;
      __builtin_amdgcn_global_load_lds(TO_GLB(gb),
          TO_LDS((char*)Bs + (i * 256 + wid * 64) * 16), 16, 0, 0);
    }
    __syncthreads();
    s16x8 af[4], bfr[4];
#pragma unroll
    for (int m = 0; m < 4; m++) {
      int r = wr * 64 + m * 16 + (lane & 15);
      af[m] = *(const s16x8*)((const char*)As + r * 64 + (lane >> 4) * 16);
    }
#pragma unroll
    for (int n = 0; n < 4; n++) {
      int r = wc * 64 + n * 16 + (lane & 15);
      bfr[n] = *(const s16x8*)((const char*)Bs + r * 64 + (lane >> 4) * 16);
    }
#pragma unroll
    for (int m = 0; m < 4; m++)
#pragma unroll
      for (int n = 0; n < 4; n++)
        acc[m][n] = __builtin_amdgcn_mfma_f32_16x16x32_bf16(af[m], bfr[n], acc[m][n], 0, 0, 0);
  }

#pragma unroll
  for (int m = 0; m < 4; m++)
#pragma unroll
    for (int n = 0; n < 4; n++)
#pragma unroll
      for (int j = 0; j < 4; j++) {
        size_t row = tm + wr * 64 + m * 16 + ((lane >> 4) << 2) + j;
        int col = (int)tn + wc * 64 + n * 16 + (lane & 15);
        float v = acc[m][n][j] + b_ih[col] + b_hh[col];
        C[row * 4096 + col] = f2bf(v);
      }
}

// ---------------- persistent LSTM scan (r6 protocol, the proven 1290us) ---
// 256 blocks = 4 batch-groups x 64 unit-groups; 512 thr, 8 waves.
// Per-step cost ~5.08us = cross-XCD LLC store-visibility + read latency
// (structural floor: r4/r5/r6 identical across protocols; r8/r10 cheaper-
// signaling variants regressed; XCD-local relays hang).
__global__ __launch_bounds__(512, 2) void lstm_scan(
    const ushort_t* __restrict__ whhb,   // W_hh bf16 [4096][1024]
    const ushort_t* __restrict__ xproj,  // bf16 [16384][4096]
    const float* __restrict__ reset,     // f32 [256*64]
    const float* __restrict__ cx,        // f32 [64*1024]
    ushort_t* __restrict__ h0buf, ushort_t* __restrict__ h1buf,
    unsigned int* __restrict__ flags,    // [256], zeroed before launch
    float* __restrict__ out_h0, float* __restrict__ out_h1,
    float* __restrict__ out_cs)
{
  __shared__ char smem[43520];
  char* hs = smem;                        // h tile [16][2048B], XOR-swizzled
  float* gsh = (float*)(smem + 32768);    // [2 kh][16 batch][84] gate partials

  const int t = threadIdx.x;
  const int lane = t & 63;
  const int w = t >> 6;
  const int ns = w & 3;          // gate section
  const int kh = w >> 2;         // K half
  const int j16 = lane & 15;
  const int q = lane >> 4;
  const int blk = blockIdx.x;
  const int bg = blk >> 6;       // batch group 0..3
  const int ug = blk & 63;       // unit group 0..63
  const int b0 = bg * 16;
  const int u0 = ug * 16;

  // ---- permanent weight fragments: 16 x s16x8 = 64 VGPR ----
  s16x8 bfrag[16];
  {
    const ushort_t* wrow = whhb + ((size_t)(ns * 1024 + u0 + j16)) * 1024 + kh * 512 + q * 8;
#pragma unroll
    for (int kk = 0; kk < 16; kk++)
      bfrag[kk] = *(const s16x8*)(wrow + kk * 32);
  }
#pragma unroll
  for (int kk = 0; kk < 16; kk++)
    asm volatile("" : "+v"(bfrag[kk]));

  // ---- persistent cell state: threads 0..255 own one (b_local, lu) cell ----
  const int b_local = t >> 4;    // valid for t<256: 0..15
  const int lu = t & 15;
  const bool upd = (t < 256);
  float c_reg = 0.0f;
  if (upd) c_reg = cx[(size_t)(b0 + b_local) * 1024 + u0 + lu];

  // staging coords: thread loads row sr, 64B chunk sc
  const int sr = t & 15;
  const int sc = t >> 4;         // 0..31
  const int swz = (sr & 7) << 4;
  const s16x8 zv = {0, 0, 0, 0, 0, 0, 0, 0};
  const f32x4 fzero = {0.f, 0.f, 0.f, 0.f};

  for (int s = 0; s < 256; s++) {
    const ushort_t* hc = (s & 1) ? h1buf : h0buf;
    ushort_t* hn = (s & 1) ? h0buf : h1buf;

    // prefetch xproj/reset (independent of h -> latency hides under poll)
    float xv0 = 0.f, xv1 = 0.f, xv2 = 0.f, xv3 = 0.f, m2 = 0.f;
    if (upd) {
      const ushort_t* xpp = xproj + ((size_t)s * 64 + b0 + b_local) * 4096 + u0 + lu;
      xv0 = bf2f(xpp[0]);
      xv1 = bf2f(xpp[1024]);
      xv2 = bf2f(xpp[2048]);
      xv3 = bf2f(xpp[3072]);
      m2 = 1.0f - reset[s * 64 + b0 + b_local];
    }
    float mrow = reset[s * 64 + b0 + sr];

    // ---- per-wave poll of the 64 producers of our batch-group ----
    if (s > 0) {
      const unsigned int* fp = flags + bg * 64 + lane;
      while (__hip_atomic_load(fp, __ATOMIC_RELAXED, __HIP_MEMORY_SCOPE_AGENT)
             < (unsigned int)s) {}
      asm volatile("" ::: "memory");   // keep staging loads below the poll
    }

    // ---- stage h[16][1024] -> LDS: 4 x b128 sc0/sc1 loads (LLC-coherent) ----
    {
      const char* srcp = (const char*)(hc + (size_t)(b0 + sr) * 1024 + sc * 32);
      s16x8 v0, v1, v2, v3;
      asm volatile("global_load_dwordx4 %0, %1, off sc0 sc1" : "=v"(v0) : "v"(srcp));
      asm volatile("global_load_dwordx4 %0, %1, off offset:16 sc0 sc1" : "=v"(v1) : "v"(srcp));
      asm volatile("global_load_dwordx4 %0, %1, off offset:32 sc0 sc1" : "=v"(v2) : "v"(srcp));
      asm volatile("global_load_dwordx4 %0, %1, off offset:48 sc0 sc1" : "=v"(v3) : "v"(srcp));
      asm volatile("s_waitcnt vmcnt(0)" ::: "memory");
      __builtin_amdgcn_sched_barrier(0);
      if (mrow != 0.0f) { v0 = zv; v1 = zv; v2 = zv; v3 = zv; }  // episode reset
      const int base = sr * 2048 + sc * 64;
      *(s16x8*)(hs + ((base + 0)  ^ swz)) = v0;
      *(s16x8*)(hs + ((base + 16) ^ swz)) = v1;
      *(s16x8*)(hs + ((base + 32) ^ swz)) = v2;
      *(s16x8*)(hs + ((base + 48) ^ swz)) = v3;
    }
    __syncthreads();

    // ---- MFMA: wave computes gates[16 batch][16 units of gate ns], K=512 ----
    f32x4 acc = fzero;
#pragma unroll
    for (int kk = 0; kk < 16; kk++) {
      int off = (j16 * 2048 + kh * 1024 + kk * 64 + q * 16) ^ ((j16 & 7) << 4);
      s16x8 a = *(const s16x8*)(hs + off);
      acc = __builtin_amdgcn_mfma_f32_16x16x32_bf16(a, bfrag[kk], acc, 0, 0, 0);
    }
#pragma unroll
    for (int kk = 0; kk < 16; kk++)
      asm volatile("" : "+v"(bfrag[kk]));

    // ---- stash partial gates: gsh[kh][batch=q*4+jj][ns*16+j16] ----
#pragma unroll
    for (int jj = 0; jj < 4; jj++)
      gsh[kh * 1344 + (q * 4 + jj) * 84 + ns * 16 + j16] = acc[jj];
    __syncthreads();

    // ---- cell update (threads 0..255, 1 cell each) ----
    float hv = 0.0f, cn = 0.0f;
    if (upd) {
      const float* g0p = gsh + b_local * 84;
      const float* g1p = gsh + 1344 + b_local * 84;
      float gv0 = g0p[lu]      + g1p[lu]      + xv0;
      float gv1 = g0p[16 + lu] + g1p[16 + lu] + xv1;
      float gv2 = g0p[32 + lu] + g1p[32 + lu] + xv2;
      float gv3 = g0p[48 + lu] + g1p[48 + lu] + xv3;
      float ii = sigm(gv0), ff = sigm(gv1), G = tanh_f(gv2), oo = sigm(gv3);
      cn = ff * (c_reg * m2) + ii * G;
      hv = oo * tanh_f(cn);
      c_reg = cn;

      // h store: pack lane pairs -> one 4B agent-scope (sc1) store
      unsigned int mybits = (unsigned int)f2bf(hv);
      unsigned int pb = (unsigned int)__shfl_xor((int)mybits, 1, 64);
      if ((t & 1) == 0) {
        unsigned int pack = mybits | (pb << 16);
        __hip_atomic_store(
            (unsigned int*)(hn + (size_t)(b0 + b_local) * 1024 + u0 + lu),
            pack, __ATOMIC_RELAXED, __HIP_MEMORY_SCOPE_AGENT);
      }
    }

    // drain h stores, join all waves, release flag
    asm volatile("s_waitcnt vmcnt(0)" ::: "memory");
    __syncthreads();
    if (t == 0)
      __hip_atomic_store(&flags[blk], (unsigned int)(s + 1),
                         __ATOMIC_RELAXED, __HIP_MEMORY_SCOPE_AGENT);

    // ---- output stores AFTER the flag: off the critical path ----
    if (upd) {
      size_t ob = ((size_t)s * 64 + b0 + b_local) * 1024 + u0 + lu;
      out_cs[ob] = cn;
      out_h0[ob] = hv;
      out_h1[ob] = hv;
    }
  }
}

extern "C" void kernel_launch(void* const* d_in, const int* in_sizes, int n_in,
                              void* d_out, int out_size, void* d_ws, size_t ws_size,
                              hipStream_t stream) {
  const float* x     = (const float*)d_in[0];
  const float* hx    = (const float*)d_in[1];
  const float* cx    = (const float*)d_in[2];
  const float* reset = (const float*)d_in[3];
  const float* W_ih  = (const float*)d_in[4];
  const float* W_hh  = (const float*)d_in[5];
  const float* b_ih  = (const float*)d_in[6];
  const float* b_hh  = (const float*)d_in[7];
  float* out = (float*)d_out;

  char* ws = (char*)d_ws;
  ushort_t* xbf   = (ushort_t*)(ws);                  // 33,554,432 B
  ushort_t* wihb  = (ushort_t*)(ws + 33554432);       //  8,388,608 B
  ushort_t* whhb  = (ushort_t*)(ws + 41943040);       //  8,388,608 B
  ushort_t* xproj = (ushort_t*)(ws + 50331648);       // 134,217,728 B
  ushort_t* h0    = (ushort_t*)(ws + 184549376);      // 131,072 B
  ushort_t* h1    = (ushort_t*)(ws + 184680448);      // 131,072 B
  unsigned int* flags = (unsigned int*)(ws + 184811520);  // 1,024 B

  hipMemsetAsync(flags, 0, 1024, stream);
  hipLaunchKernelGGL(prep_all, dim3(2048), dim3(256), 0, stream,
                     x, W_ih, W_hh, hx, xbf, wihb, whhb, h0);
  hipLaunchKernelGGL(gemm_xproj, dim3(128, 32), dim3(256), 0, stream,
                     xbf, wihb, b_ih, b_hh, xproj);

  float* oh0 = out;
  float* oh1 = out + 16777216;
  float* ocs = out + 33554432;

  const ushort_t* whhb_c = whhb;
  const ushort_t* xproj_c = xproj;
  void* args[] = {(void*)&whhb_c, (void*)&xproj_c, (void*)&reset, (void*)&cx,
                  (void*)&h0, (void*)&h1, (void*)&flags,
                  (void*)&oh0, (void*)&oh1, (void*)&ocs};
  hipLaunchCooperativeKernel((void*)lstm_scan, dim3(256), dim3(512), args, 0, stream);
}